// Round 1
// baseline (99554.529 us; speedup 1.0000x reference)
//
#include <hip/hip_runtime.h>

#define DEPTH 10
#define HID 48
#define IN_DIM 784
#define OUT_DIM 10
#define STEPS 20
#define LR 0.1f
#define BATCH 65536

#define BLOCK 512
#define SPB 128            // samples per block = BLOCK/4
#define RS 52              // padded row stride (floats) for transposed weights

// LDS layout (float offsets)
#define WHT_OFF 0                      // 9*48*RS = 22464 : Wht[i][k*RS+j] = Wh[i][j][k]
#define WOUT_OFF 22464                 // 10*RS = 520     : WoutT-ish rows: Wout[c][k] at c*RS+k
#define BH_OFF  22984                  // 9*48 = 432
#define BOUT_OFF 23416                 // 16
#define W0T_OFF 23432                  // CHUNK*48 = 5376 : W0t[k][j] for current chunk
#define CHUNK 112                      // 7 chunks * 112 = 784
#define LDS_FLOATS (23432 + CHUNK*48)  // 28808 floats = 115232 bytes

extern __shared__ float lds[];

__global__ __launch_bounds__(BLOCK, 2) void pcnet_kernel(
    const float* __restrict__ x, const int* __restrict__ target,
    const float* __restrict__ W0, const float* __restrict__ b0,
    const float* __restrict__ Wh, const float* __restrict__ bh,
    const float* __restrict__ Wout, const float* __restrict__ bout,
    float* __restrict__ out)
{
    const int t = threadIdx.x;

    // ---- stage Wh transposed: Wht[i][k*RS + j] = Wh[i][j][k]
    for (int idx = t; idx < 9 * 48 * 48; idx += BLOCK) {
        int i = idx / 2304;
        int r = idx - i * 2304;
        int j = r / 48;
        int k = r - j * 48;
        lds[WHT_OFF + i * 48 * RS + k * RS + j] = Wh[idx];
    }
    // ---- Wout rows padded: lds[WOUT_OFF + c*RS + k] = Wout[c][k]
    for (int idx = t; idx < 10 * 48; idx += BLOCK) {
        int c = idx / 48, k = idx - c * 48;
        lds[WOUT_OFF + c * RS + k] = Wout[idx];
    }
    for (int idx = t; idx < 9 * 48; idx += BLOCK) lds[BH_OFF + idx] = bh[idx];
    if (t < 10) lds[BOUT_OFF + t] = bout[t];

    const int lane = t & 63;
    const int wv = t >> 6;
    const int g = lane & 3;        // component quarter 0..3
    const int sloc = lane >> 2;    // sample within wave 0..15
    const int b = blockIdx.x * SPB + wv * 16 + sloc;
    const int base_lane = lane & ~3;
    const int j0 = g * 12;

    float v[DEPTH][12];
    float a0[12];

    // ======== forward layer 0: a0 = relu(x @ W0^T + b0), W0 staged in chunks ========
    float acc[12];
    #pragma unroll
    for (int jj = 0; jj < 12; jj++) acc[jj] = b0[j0 + jj];

    for (int ch = 0; ch < IN_DIM / CHUNK; ch++) {
        __syncthreads();   // also guards initial Wht staging (ch==0) and prev compute
        for (int idx = t; idx < CHUNK * 48; idx += BLOCK) {
            int j = idx / CHUNK;
            int kl = idx - j * CHUNK;    // consecutive t -> consecutive kl : coalesced
            lds[W0T_OFF + kl * 48 + j] = W0[j * IN_DIM + ch * CHUNK + kl];
        }
        __syncthreads();
        const float* xb = x + (size_t)b * IN_DIM + ch * CHUNK;
        for (int k4 = 0; k4 < CHUNK; k4 += 4) {
            float4 xv = *(const float4*)(xb + k4);
            const float xs[4] = { xv.x, xv.y, xv.z, xv.w };
            #pragma unroll
            for (int f = 0; f < 4; f++) {
                const float* wrow = &lds[W0T_OFF + (k4 + f) * 48 + j0];
                #pragma unroll
                for (int jj = 0; jj < 12; jj++) acc[jj] = fmaf(wrow[jj], xs[f], acc[jj]);
            }
        }
    }
    __syncthreads();
    #pragma unroll
    for (int jj = 0; jj < 12; jj++) { a0[jj] = fmaxf(acc[jj], 0.f); v[0][jj] = a0[jj]; }

    // matvec: pre[jj] = bh[layer][j0+jj] + sum_k Wh[layer][j0+jj][k] * src[k]
    auto matvec = [&](const float (&src)[12], int layer, float (&pre)[12]) {
        const float* bhp = &lds[BH_OFF + layer * 48 + j0];
        #pragma unroll
        for (int jj = 0; jj < 12; jj++) pre[jj] = bhp[jj];
        const float* wl = &lds[WHT_OFF + layer * 48 * RS];
        for (int q = 0; q < 4; q++) {
            #pragma unroll
            for (int r = 0; r < 12; r++) {
                float vk = __shfl(src[r], base_lane + q, 64);
                const float* wrow = wl + (q * 12 + r) * RS + j0;
                #pragma unroll
                for (int jj = 0; jj < 12; jj++) pre[jj] = fmaf(wrow[jj], vk, pre[jj]);
            }
        }
    };

    // ======== forward layers 1..9 ========
    #pragma unroll
    for (int L = 1; L < DEPTH; L++) {
        float pre[12];
        matvec(v[L - 1], L - 1, pre);
        #pragma unroll
        for (int jj = 0; jj < 12; jj++) v[L][jj] = fmaxf(pre[jj], 0.f);
    }

    const int tgt = target[b];

    // ======== settling: 20 steps ========
    for (int s = 0; s < STEPS; s++) {
        float err_prev[12];
        #pragma unroll
        for (int jj = 0; jj < 12; jj++) err_prev[jj] = v[0][jj] - a0[jj];

        #pragma unroll
        for (int i = 1; i <= 9; i++) {
            float pre[12];
            matvec(v[i - 1], i - 1, pre);
            float err[12], me[12];
            #pragma unroll
            for (int jj = 0; jj < 12; jj++) {
                float rel = fmaxf(pre[jj], 0.f);
                err[jj] = v[i][jj] - rel;
                me[jj] = (pre[jj] > 0.f) ? err[jj] : 0.f;
            }
            // td[c] = sum_j Wh[i-1][j][c] * me[j], for own c = j0+kk  (rows of Wht)
            float td[12];
            #pragma unroll
            for (int kk = 0; kk < 12; kk++) td[kk] = 0.f;
            const float* wl = &lds[WHT_OFF + (i - 1) * 48 * RS];
            for (int q = 0; q < 4; q++) {
                float mf[12];
                #pragma unroll
                for (int r = 0; r < 12; r++) mf[r] = __shfl(me[r], base_lane + q, 64);
                #pragma unroll
                for (int kk = 0; kk < 12; kk++) {
                    const float* wrow = wl + (j0 + kk) * RS + q * 12;
                    #pragma unroll
                    for (int r = 0; r < 12; r++) td[kk] = fmaf(wrow[r], mf[r], td[kk]);
                }
            }
            // update v[i-1]
            #pragma unroll
            for (int jj = 0; jj < 12; jj++) {
                float nv = v[i - 1][jj] - LR * (err_prev[jj] - td[jj]);
                v[i - 1][jj] = fminf(fmaxf(nv, -10.f), 10.f);
                err_prev[jj] = err[jj];
            }
        }

        // ---- output layer i = 10 ----
        float pp[OUT_DIM];
        #pragma unroll
        for (int c = 0; c < OUT_DIM; c++) {
            const float* wrow = &lds[WOUT_OFF + c * RS + j0];
            float a = 0.f;
            #pragma unroll
            for (int kk = 0; kk < 12; kk++) a = fmaf(wrow[kk], v[9][kk], a);
            pp[c] = a;
        }
        #pragma unroll
        for (int c = 0; c < OUT_DIM; c++) {
            pp[c] += __shfl_xor(pp[c], 1, 64);
            pp[c] += __shfl_xor(pp[c], 2, 64);
        }
        float e10[OUT_DIM];
        #pragma unroll
        for (int c = 0; c < OUT_DIM; c++) {
            float pred = pp[c] + lds[BOUT_OFF + c];
            e10[c] = ((c == tgt) ? 1.f : 0.f) - pred;
        }
        float td10[12];
        #pragma unroll
        for (int kk = 0; kk < 12; kk++) {
            float a = 0.f;
            #pragma unroll
            for (int c = 0; c < OUT_DIM; c++)
                a = fmaf(lds[WOUT_OFF + c * RS + j0 + kk], e10[c], a);
            td10[kk] = a;
        }
        #pragma unroll
        for (int jj = 0; jj < 12; jj++) {
            float nv = v[9][jj] - LR * (err_prev[jj] - td10[jj]);
            v[9][jj] = fminf(fmaxf(nv, -10.f), 10.f);
        }
    }

    // ======== write V: out[L][b][h] ========
    #pragma unroll
    for (int L = 0; L < DEPTH; L++) {
        float4* o4 = (float4*)(out + (size_t)L * BATCH * HID + (size_t)b * HID + j0);
        o4[0] = make_float4(v[L][0], v[L][1], v[L][2], v[L][3]);
        o4[1] = make_float4(v[L][4], v[L][5], v[L][6], v[L][7]);
        o4[2] = make_float4(v[L][8], v[L][9], v[L][10], v[L][11]);
    }
}

extern "C" void kernel_launch(void* const* d_in, const int* in_sizes, int n_in,
                              void* d_out, int out_size, void* d_ws, size_t ws_size,
                              hipStream_t stream) {
    const float* x      = (const float*)d_in[0];
    const int*   target = (const int*)d_in[1];
    const float* W0     = (const float*)d_in[2];
    const float* b0     = (const float*)d_in[3];
    const float* Wh     = (const float*)d_in[4];
    const float* bh     = (const float*)d_in[5];
    const float* Wout   = (const float*)d_in[6];
    const float* bout   = (const float*)d_in[7];
    float* out = (float*)d_out;

    const int lds_bytes = LDS_FLOATS * 4;
    hipFuncSetAttribute((const void*)pcnet_kernel,
                        hipFuncAttributeMaxDynamicSharedMemorySize, lds_bytes);

    dim3 grid(BATCH / SPB);   // 512 blocks
    dim3 block(BLOCK);        // 512 threads = 8 waves, 128 samples/block
    pcnet_kernel<<<grid, block, lds_bytes, stream>>>(x, target, W0, b0, Wh, bh, Wout, bout, out);
}

// Round 2
// 7026.160 us; speedup vs baseline: 14.1691x; 14.1691x over previous
//
#include <hip/hip_runtime.h>

#define DEPTH 10
#define HID 48
#define IN_DIM 784
#define OUT_DIM 10
#define STEPS 20
#define LR 0.1f
#define BATCH 65536

#define BLOCK 512
#define SPB 128            // samples per block = BLOCK/4
#define RS 52              // padded row stride (floats) for transposed weights

// LDS layout (float offsets)
#define WHT_OFF 0                      // 9*48*RS = 22464 : Wht[i][k*RS+j] = Wh[i][j][k]
#define WOUT_OFF 22464                 // 10*RS = 520     : Wout[c][k] at c*RS+k
#define BH_OFF  22984                  // 9*48 = 432
#define BOUT_OFF 23416                 // 16
#define W0T_OFF 23432                  // CHUNK*48 = 5376 : W0t[k][j] for current chunk
#define CHUNK 112                      // 7 chunks * 112 = 784
#define LDS_FLOATS (23432 + CHUNK*48)  // 28808 floats = 115232 bytes

extern __shared__ float lds[];

__global__ __launch_bounds__(BLOCK, 1) __attribute__((amdgpu_waves_per_eu(1, 2)))
void pcnet_kernel(
    const float* __restrict__ x, const int* __restrict__ target,
    const float* __restrict__ W0, const float* __restrict__ b0,
    const float* __restrict__ Wh, const float* __restrict__ bh,
    const float* __restrict__ Wout, const float* __restrict__ bout,
    float* __restrict__ out)
{
    const int t = threadIdx.x;

    // ---- stage Wh transposed: Wht[i][k*RS + j] = Wh[i][j][k]
    for (int idx = t; idx < 9 * 48 * 48; idx += BLOCK) {
        int i = idx / 2304;
        int r = idx - i * 2304;
        int j = r / 48;
        int k = r - j * 48;
        lds[WHT_OFF + i * 48 * RS + k * RS + j] = Wh[idx];
    }
    // ---- Wout rows padded: lds[WOUT_OFF + c*RS + k] = Wout[c][k]
    for (int idx = t; idx < 10 * 48; idx += BLOCK) {
        int c = idx / 48, k = idx - c * 48;
        lds[WOUT_OFF + c * RS + k] = Wout[idx];
    }
    for (int idx = t; idx < 9 * 48; idx += BLOCK) lds[BH_OFF + idx] = bh[idx];
    if (t < 10) lds[BOUT_OFF + t] = bout[t];

    const int lane = t & 63;
    const int wv = t >> 6;
    const int g = lane & 3;        // component quarter 0..3
    const int sloc = lane >> 2;    // sample within wave 0..15
    const int b = blockIdx.x * SPB + wv * 16 + sloc;
    const int base_lane = lane & ~3;
    const int j0 = g * 12;

    float v[DEPTH][12];
    float a0[12];

    // ======== forward layer 0: a0 = relu(x @ W0^T + b0), W0 staged in chunks ========
    float acc[12];
    #pragma unroll
    for (int jj = 0; jj < 12; jj++) acc[jj] = b0[j0 + jj];

    for (int ch = 0; ch < IN_DIM / CHUNK; ch++) {
        __syncthreads();   // also guards initial Wht staging (ch==0) and prev compute
        for (int idx = t; idx < CHUNK * 48; idx += BLOCK) {
            int j = idx / CHUNK;
            int kl = idx - j * CHUNK;    // consecutive t -> consecutive kl : coalesced
            lds[W0T_OFF + kl * 48 + j] = W0[j * IN_DIM + ch * CHUNK + kl];
        }
        __syncthreads();
        const float* xb = x + (size_t)b * IN_DIM + ch * CHUNK;
        for (int k4 = 0; k4 < CHUNK; k4 += 4) {
            float4 xv = *(const float4*)(xb + k4);
            const float xs[4] = { xv.x, xv.y, xv.z, xv.w };
            #pragma unroll
            for (int f = 0; f < 4; f++) {
                const float* wrow = &lds[W0T_OFF + (k4 + f) * 48 + j0];
                #pragma unroll
                for (int jj = 0; jj < 12; jj++) acc[jj] = fmaf(wrow[jj], xs[f], acc[jj]);
            }
        }
    }
    __syncthreads();
    #pragma unroll
    for (int jj = 0; jj < 12; jj++) { a0[jj] = fmaxf(acc[jj], 0.f); v[0][jj] = a0[jj]; }

    // matvec: pre[jj] = bh[layer][j0+jj] + sum_k Wh[layer][j0+jj][k] * src[k]
    auto matvec = [&](const float (&src)[12], int layer, float (&pre)[12]) {
        const float* bhp = &lds[BH_OFF + layer * 48 + j0];
        #pragma unroll
        for (int jj = 0; jj < 12; jj++) pre[jj] = bhp[jj];
        const float* wl = &lds[WHT_OFF + layer * 48 * RS];
        #pragma unroll
        for (int q = 0; q < 4; q++) {
            #pragma unroll
            for (int r = 0; r < 12; r++) {
                float vk = __shfl(src[r], base_lane + q, 64);
                const float* wrow = wl + (q * 12 + r) * RS + j0;
                #pragma unroll
                for (int jj = 0; jj < 12; jj++) pre[jj] = fmaf(wrow[jj], vk, pre[jj]);
            }
        }
    };

    // ======== forward layers 1..9 ========
    #pragma unroll
    for (int L = 1; L < DEPTH; L++) {
        float pre[12];
        matvec(v[L - 1], L - 1, pre);
        #pragma unroll
        for (int jj = 0; jj < 12; jj++) v[L][jj] = fmaxf(pre[jj], 0.f);
    }

    const int tgt = target[b];

    // ======== settling: 20 steps ========
    for (int s = 0; s < STEPS; s++) {
        float err_prev[12];
        #pragma unroll
        for (int jj = 0; jj < 12; jj++) err_prev[jj] = v[0][jj] - a0[jj];

        #pragma unroll
        for (int i = 1; i <= 9; i++) {
            float pre[12];
            matvec(v[i - 1], i - 1, pre);
            float err[12], me[12];
            #pragma unroll
            for (int jj = 0; jj < 12; jj++) {
                float rel = fmaxf(pre[jj], 0.f);
                err[jj] = v[i][jj] - rel;
                me[jj] = (pre[jj] > 0.f) ? err[jj] : 0.f;
            }
            // td[c] = sum_j Wh[i-1][j][c] * me[j], for own c = j0+kk  (rows of Wht)
            float td[12];
            #pragma unroll
            for (int kk = 0; kk < 12; kk++) td[kk] = 0.f;
            const float* wl = &lds[WHT_OFF + (i - 1) * 48 * RS];
            #pragma unroll
            for (int q = 0; q < 4; q++) {
                float mf[12];
                #pragma unroll
                for (int r = 0; r < 12; r++) mf[r] = __shfl(me[r], base_lane + q, 64);
                #pragma unroll
                for (int kk = 0; kk < 12; kk++) {
                    const float* wrow = wl + (j0 + kk) * RS + q * 12;
                    #pragma unroll
                    for (int r = 0; r < 12; r++) td[kk] = fmaf(wrow[r], mf[r], td[kk]);
                }
            }
            // update v[i-1]
            #pragma unroll
            for (int jj = 0; jj < 12; jj++) {
                float nv = v[i - 1][jj] - LR * (err_prev[jj] - td[jj]);
                v[i - 1][jj] = fminf(fmaxf(nv, -10.f), 10.f);
                err_prev[jj] = err[jj];
            }
        }

        // ---- output layer i = 10 ----
        float pp[OUT_DIM];
        #pragma unroll
        for (int c = 0; c < OUT_DIM; c++) {
            const float* wrow = &lds[WOUT_OFF + c * RS + j0];
            float a = 0.f;
            #pragma unroll
            for (int kk = 0; kk < 12; kk++) a = fmaf(wrow[kk], v[9][kk], a);
            pp[c] = a;
        }
        #pragma unroll
        for (int c = 0; c < OUT_DIM; c++) {
            pp[c] += __shfl_xor(pp[c], 1, 64);
            pp[c] += __shfl_xor(pp[c], 2, 64);
        }
        float e10[OUT_DIM];
        #pragma unroll
        for (int c = 0; c < OUT_DIM; c++) {
            float pred = pp[c] + lds[BOUT_OFF + c];
            e10[c] = ((c == tgt) ? 1.f : 0.f) - pred;
        }
        float td10[12];
        #pragma unroll
        for (int kk = 0; kk < 12; kk++) {
            float a = 0.f;
            #pragma unroll
            for (int c = 0; c < OUT_DIM; c++)
                a = fmaf(lds[WOUT_OFF + c * RS + j0 + kk], e10[c], a);
            td10[kk] = a;
        }
        #pragma unroll
        for (int jj = 0; jj < 12; jj++) {
            float nv = v[9][jj] - LR * (err_prev[jj] - td10[jj]);
            v[9][jj] = fminf(fmaxf(nv, -10.f), 10.f);
        }
    }

    // ======== write V: out[L][b][h] ========
    #pragma unroll
    for (int L = 0; L < DEPTH; L++) {
        float4* o4 = (float4*)(out + (size_t)L * BATCH * HID + (size_t)b * HID + j0);
        o4[0] = make_float4(v[L][0], v[L][1], v[L][2], v[L][3]);
        o4[1] = make_float4(v[L][4], v[L][5], v[L][6], v[L][7]);
        o4[2] = make_float4(v[L][8], v[L][9], v[L][10], v[L][11]);
    }
}

extern "C" void kernel_launch(void* const* d_in, const int* in_sizes, int n_in,
                              void* d_out, int out_size, void* d_ws, size_t ws_size,
                              hipStream_t stream) {
    const float* x      = (const float*)d_in[0];
    const int*   target = (const int*)d_in[1];
    const float* W0     = (const float*)d_in[2];
    const float* b0     = (const float*)d_in[3];
    const float* Wh     = (const float*)d_in[4];
    const float* bh     = (const float*)d_in[5];
    const float* Wout   = (const float*)d_in[6];
    const float* bout   = (const float*)d_in[7];
    float* out = (float*)d_out;

    const int lds_bytes = LDS_FLOATS * 4;
    hipFuncSetAttribute((const void*)pcnet_kernel,
                        hipFuncAttributeMaxDynamicSharedMemorySize, lds_bytes);

    dim3 grid(BATCH / SPB);   // 512 blocks
    dim3 block(BLOCK);        // 512 threads = 8 waves, 128 samples/block
    pcnet_kernel<<<grid, block, lds_bytes, stream>>>(x, target, W0, b0, Wh, bh, Wout, bout, out);
}

// Round 3
// 1799.669 us; speedup vs baseline: 55.3182x; 3.9041x over previous
//
#include <hip/hip_runtime.h>
#include <stdint.h>

typedef __attribute__((ext_vector_type(8))) _Float16 half8;
typedef __attribute__((ext_vector_type(4))) float f32x4;
typedef __attribute__((ext_vector_type(4))) uint32_t uint4v;

#define LR 0.1f
#define BLOCK 512

// LDS byte offsets
// WFRAG: [9 layers][2 dir][3 tiles][2 ks][64 lanes][16B] = 110592
#define WOUTP_OFF  110592   // pred B-frags: [2 ks][64][16B] = 2048
#define WOUTT_OFF  112640   // td10 B-frags: [3 tiles][64][16B] = 3072
#define BH_OFF_B   115712   // bh f32: 9*48*4 = 1728
#define BOUT_OFF_B 117440   // bout f32: 64
#define VT_OFF_B   117504   // per-wave transpose tile: 864 u32 = 3456B * 8 waves
#define VT_STRIDE  3456
#define LDS_BYTES  (VT_OFF_B + 8*VT_STRIDE)   // 145152

extern __shared__ unsigned char smem[];

// pack f32 -> (f16 hi << 16) | f16 lo  (2-term split)
#define PACK_SPLIT(VAL, W) do { \
  float _v0 = (VAL); \
  _Float16 _hh = (_Float16)_v0; \
  float _hf = (float)_hh; \
  _Float16 _ll = (_Float16)(_v0 - _hf); \
  W = ((uint32_t)__builtin_bit_cast(unsigned short, _hh) << 16) | \
      (uint32_t)__builtin_bit_cast(unsigned short, _ll); \
} while(0)

// 48x48 matvec for 16 samples via MFMA. SRC/DST: float[12] in C-layout
// (idx = tile*4 + r ; value of sample 4*bq+r, comp n+16*tile).
// WFB: byte base of B-frag storage (3 tiles x 2 ks x 64 lanes x 16B).
// HASBIAS: compile-time 0/1; BIASOFF: float offset into bh LDS.
#define MV48(SRC, WFB, BIASOFF, HASBIAS, DST) do { \
  _Pragma("unroll") \
  for (int _t = 0; _t < 3; ++_t) { \
    _Pragma("unroll") \
    for (int _r = 0; _r < 4; ++_r) { \
      uint32_t _w; PACK_SPLIT(SRC[_t*4+_r], _w); \
      vtu[(4*bq+_r)*52 + n + 16*_t] = _w; \
    } \
  } \
  half8 _Ah[2], _Al[2]; \
  _Pragma("unroll") \
  for (int _ks = 0; _ks < 2; ++_ks) { \
    const uint32_t* _vp = vtu + n*52 + _ks*32 + bq*8; \
    uint4v _wa = *(const uint4v*)_vp; \
    uint4v _wb = *(const uint4v*)(_vp + 4); \
    union { half8 h; uint32_t u[4]; } _ah, _al; \
    _Pragma("unroll") \
    for (int _p = 0; _p < 2; ++_p) { \
      _ah.u[_p]   = (_wa[2*_p] >> 16) | (_wa[2*_p+1] & 0xFFFF0000u); \
      _al.u[_p]   = (_wa[2*_p] & 0xFFFFu) | (_wa[2*_p+1] << 16); \
      _ah.u[_p+2] = (_wb[2*_p] >> 16) | (_wb[2*_p+1] & 0xFFFF0000u); \
      _al.u[_p+2] = (_wb[2*_p] & 0xFFFFu) | (_wb[2*_p+1] << 16); \
    } \
    _Ah[_ks] = _ah.h; _Al[_ks] = _al.h; \
  } \
  _Pragma("unroll") \
  for (int _t = 0; _t < 3; ++_t) { \
    float _bv = (HASBIAS) ? bhf[(BIASOFF) + n + 16*_t] : 0.f; \
    f32x4 _acc = { _bv, _bv, _bv, _bv }; \
    _Pragma("unroll") \
    for (int _ks = 0; _ks < 2; ++_ks) { \
      half8 _B = *(const half8*)(smem + (WFB) + (_t*2+_ks)*1024 + lane*16); \
      _acc = __builtin_amdgcn_mfma_f32_16x16x32_f16(_Ah[_ks], _B, _acc, 0, 0, 0); \
      _acc = __builtin_amdgcn_mfma_f32_16x16x32_f16(_Al[_ks], _B, _acc, 0, 0, 0); \
    } \
    _Pragma("unroll") \
    for (int _r = 0; _r < 4; ++_r) DST[_t*4+_r] = _acc[_r]; \
  } \
} while(0)

#define LAYER_STEP(I) do { \
  float _pre[12], _err[12], _me[12], _td[12]; \
  MV48(v[(I)-1], ((I)-1)*12288, ((I)-1)*48, 1, _pre); \
  _Pragma("unroll") \
  for (int _q = 0; _q < 12; ++_q) { \
    float _rl = fmaxf(_pre[_q], 0.f); \
    _err[_q] = v[I][_q] - _rl; \
    _me[_q] = (_pre[_q] > 0.f) ? _err[_q] : 0.f; \
  } \
  MV48(_me, ((I)-1)*12288 + 6144, 0, 0, _td); \
  _Pragma("unroll") \
  for (int _q = 0; _q < 12; ++_q) { \
    float _nv = v[(I)-1][_q] - LR*(ep[_q] - _td[_q]); \
    v[(I)-1][_q] = fminf(fmaxf(_nv, -10.f), 10.f); \
    ep[_q] = _err[_q]; \
  } \
} while(0)

#define FWD(I) do { \
  float _pre[12]; \
  MV48(v[(I)-1], ((I)-1)*12288, ((I)-1)*48, 1, _pre); \
  _Pragma("unroll") \
  for (int _q = 0; _q < 12; ++_q) v[I][_q] = fmaxf(_pre[_q], 0.f); \
} while(0)

__global__ __launch_bounds__(BLOCK, 1)
void pcnet_kernel(const float* __restrict__ x, const int* __restrict__ target,
                  const float* __restrict__ W0, const float* __restrict__ b0,
                  const float* __restrict__ Wh, const float* __restrict__ bh,
                  const float* __restrict__ Wout, const float* __restrict__ bout,
                  float* __restrict__ out)
{
    const int t = threadIdx.x;
    const int lane = t & 63;
    const int wv = t >> 6;
    float* ldsf = (float*)smem;
    const float* bhf = (const float*)(smem + BH_OFF_B);

    const int bsamp0 = blockIdx.x*128 + wv*16;   // wave's first sample

    // ======== phase 0: a0 = relu(x@W0^T + b0), old 4-lane-quarter mapping ========
    const int g = lane & 3, sloc = lane >> 2;
    const int bOld = bsamp0 + sloc;
    const int j0 = g*12;
    float acc0[12];
    #pragma unroll
    for (int jj = 0; jj < 12; jj++) acc0[jj] = b0[j0+jj];
    for (int ch = 0; ch < 7; ch++) {
        __syncthreads();
        for (int idx = t; idx < 112*48; idx += BLOCK) {
            int j = idx / 112, kl = idx - j*112;
            ldsf[kl*48 + j] = W0[j*784 + ch*112 + kl];
        }
        __syncthreads();
        const float* xb = x + (size_t)bOld*784 + ch*112;
        for (int k4 = 0; k4 < 112; k4 += 4) {
            float4 xv = *(const float4*)(xb + k4);
            float xs[4] = {xv.x, xv.y, xv.z, xv.w};
            #pragma unroll
            for (int f = 0; f < 4; f++) {
                const float* wr = &ldsf[(k4+f)*48 + j0];
                #pragma unroll
                for (int jj = 0; jj < 12; jj++) acc0[jj] = fmaf(wr[jj], xs[f], acc0[jj]);
            }
        }
    }

    // remap a0 -> C-layout via per-wave VT tile (f32 view)
    float* vtf = (float*)(smem + VT_OFF_B + wv*VT_STRIDE);
    uint32_t* vtu = (uint32_t*)(smem + VT_OFF_B + wv*VT_STRIDE);
    #pragma unroll
    for (int jj = 0; jj < 12; jj++) vtf[sloc*52 + j0 + jj] = fmaxf(acc0[jj], 0.f);

    const int bq = lane >> 4;    // 0..3: sample block in frag
    const int n  = lane & 15;    // col within tile
    float v[10][12], a0r[12];
    #pragma unroll
    for (int tt = 0; tt < 3; tt++)
        #pragma unroll
        for (int r = 0; r < 4; r++) {
            float val = vtf[(4*bq+r)*52 + n + 16*tt];
            a0r[tt*4+r] = val; v[0][tt*4+r] = val;
        }

    // zero VT pad columns 48..51 and tail pad (avoid NaN garbage x 0 in MFMA)
    vtu[(lane>>2)*52 + 48 + (lane&3)] = 0u;
    if (lane < 32) vtu[832 + lane] = 0u;

    __syncthreads();

    // ======== stage weight frags (f16, frag-order: conflict-free 16B/lane) ========
    for (int slot = t; slot < 6912; slot += BLOCK) {
        int L = slot / 768; int rem = slot % 768;
        int dir = rem / 384; rem %= 384;
        int tl = rem / 128; rem %= 128;
        int ks = rem / 64; int LB = rem % 64;
        int row = tl*16 + (LB & 15);
        int k0 = ks*32 + (LB >> 4)*8;
        half8 hv;
        #pragma unroll
        for (int j = 0; j < 8; j++) {
            int k = k0 + j;
            float w = 0.f;
            if (k < 48) w = (dir == 0) ? Wh[L*2304 + row*48 + k] : Wh[L*2304 + k*48 + row];
            hv[j] = (_Float16)w;
        }
        *(half8*)(smem + (L*2+dir)*6144 + (tl*2+ks)*1024 + LB*16) = hv;
    }
    for (int slot = t; slot < 5*64; slot += BLOCK) {
        int which = slot / 64; int LB = slot % 64;
        half8 hv;
        if (which < 2) {          // pred B: ks = which; rows = out class c
            int c = LB & 15; int k0 = which*32 + (LB>>4)*8;
            #pragma unroll
            for (int j = 0; j < 8; j++) { int k = k0+j; hv[j] = (_Float16)((c < 10 && k < 48) ? Wout[c*48+k] : 0.f); }
            *(half8*)(smem + WOUTP_OFF + which*1024 + LB*16) = hv;
        } else {                  // td10 B tiles: rows = hidden comp, K = class (pad 32)
            int tl = which - 2; int row = tl*16 + (LB & 15); int c0 = (LB>>4)*8;
            #pragma unroll
            for (int j = 0; j < 8; j++) { int c = c0+j; hv[j] = (_Float16)((c < 10) ? Wout[c*48+row] : 0.f); }
            *(half8*)(smem + WOUTT_OFF + tl*1024 + LB*16) = hv;
        }
    }
    for (int idx = t; idx < 432; idx += BLOCK) ((float*)(smem+BH_OFF_B))[idx] = bh[idx];
    if (t < 10) ((float*)(smem+BOUT_OFF_B))[t] = bout[t];
    __syncthreads();

    // targets for this lane's 4 samples
    int tg[4];
    #pragma unroll
    for (int r = 0; r < 4; r++) tg[r] = target[bsamp0 + 4*bq + r];

    // ======== forward init layers 1..9 ========
    FWD(1); FWD(2); FWD(3); FWD(4); FWD(5); FWD(6); FWD(7); FWD(8); FWD(9);

    // ======== settling ========
    #pragma unroll 1
    for (int s = 0; s < 20; ++s) {
        float ep[12];
        #pragma unroll
        for (int q = 0; q < 12; q++) ep[q] = v[0][q] - a0r[q];

        LAYER_STEP(1); LAYER_STEP(2); LAYER_STEP(3); LAYER_STEP(4); LAYER_STEP(5);
        LAYER_STEP(6); LAYER_STEP(7); LAYER_STEP(8); LAYER_STEP(9);

        // ---- output layer ----
        {
            // VT(v9)
            #pragma unroll
            for (int tt = 0; tt < 3; tt++)
                #pragma unroll
                for (int r = 0; r < 4; r++) {
                    uint32_t w; PACK_SPLIT(v[9][tt*4+r], w);
                    vtu[(4*bq+r)*52 + n + 16*tt] = w;
                }
            half8 Ah[2], Al[2];
            #pragma unroll
            for (int ks = 0; ks < 2; ks++) {
                const uint32_t* vp = vtu + n*52 + ks*32 + bq*8;
                uint4v wa = *(const uint4v*)vp;
                uint4v wb = *(const uint4v*)(vp + 4);
                union { half8 h; uint32_t u[4]; } ah, al;
                #pragma unroll
                for (int p = 0; p < 2; p++) {
                    ah.u[p]   = (wa[2*p] >> 16) | (wa[2*p+1] & 0xFFFF0000u);
                    al.u[p]   = (wa[2*p] & 0xFFFFu) | (wa[2*p+1] << 16);
                    ah.u[p+2] = (wb[2*p] >> 16) | (wb[2*p+1] & 0xFFFF0000u);
                    al.u[p+2] = (wb[2*p] & 0xFFFFu) | (wb[2*p+1] << 16);
                }
                Ah[ks] = ah.h; Al[ks] = al.h;
            }
            float bo = (n < 10) ? ((const float*)(smem+BOUT_OFF_B))[n] : 0.f;
            f32x4 acc = {bo, bo, bo, bo};
            #pragma unroll
            for (int ks = 0; ks < 2; ks++) {
                half8 B = *(const half8*)(smem + WOUTP_OFF + ks*1024 + lane*16);
                acc = __builtin_amdgcn_mfma_f32_16x16x32_f16(Ah[ks], B, acc, 0, 0, 0);
                acc = __builtin_amdgcn_mfma_f32_16x16x32_f16(Al[ks], B, acc, 0, 0, 0);
            }
            // e10 in C-layout; stash to VT (cols 0..15 real/zero, 16..31 zero)
            #pragma unroll
            for (int r = 0; r < 4; r++) {
                float e = 0.f;
                if (n < 10) e = ((n == tg[r]) ? 1.f : 0.f) - acc[r];
                uint32_t w; PACK_SPLIT(e, w);
                vtu[(4*bq+r)*52 + n] = w;
                vtu[(4*bq+r)*52 + n + 16] = 0u;
            }
            half8 eAh, eAl;
            {
                const uint32_t* vp = vtu + n*52 + bq*8;
                uint4v wa = *(const uint4v*)vp;
                uint4v wb = *(const uint4v*)(vp + 4);
                union { half8 h; uint32_t u[4]; } ah, al;
                #pragma unroll
                for (int p = 0; p < 2; p++) {
                    ah.u[p]   = (wa[2*p] >> 16) | (wa[2*p+1] & 0xFFFF0000u);
                    al.u[p]   = (wa[2*p] & 0xFFFFu) | (wa[2*p+1] << 16);
                    ah.u[p+2] = (wb[2*p] >> 16) | (wb[2*p+1] & 0xFFFF0000u);
                    al.u[p+2] = (wb[2*p] & 0xFFFFu) | (wb[2*p+1] << 16);
                }
                eAh = ah.h; eAl = al.h;
            }
            float td10[12];
            #pragma unroll
            for (int tt = 0; tt < 3; tt++) {
                f32x4 a2 = {0.f, 0.f, 0.f, 0.f};
                half8 B = *(const half8*)(smem + WOUTT_OFF + tt*1024 + lane*16);
                a2 = __builtin_amdgcn_mfma_f32_16x16x32_f16(eAh, B, a2, 0, 0, 0);
                a2 = __builtin_amdgcn_mfma_f32_16x16x32_f16(eAl, B, a2, 0, 0, 0);
                #pragma unroll
                for (int r = 0; r < 4; r++) td10[tt*4+r] = a2[r];
            }
            #pragma unroll
            for (int q = 0; q < 12; q++) {
                float nv = v[9][q] - LR*(ep[q] - td10[q]);
                v[9][q] = fminf(fmaxf(nv, -10.f), 10.f);
            }
        }
    }

    // ======== write V ========
    #pragma unroll
    for (int L2 = 0; L2 < 10; L2++)
        #pragma unroll
        for (int tt = 0; tt < 3; tt++)
            #pragma unroll
            for (int r = 0; r < 4; r++)
                out[(size_t)L2*65536*48 + (size_t)(bsamp0 + 4*bq + r)*48 + n + 16*tt] = v[L2][tt*4+r];
}

extern "C" void kernel_launch(void* const* d_in, const int* in_sizes, int n_in,
                              void* d_out, int out_size, void* d_ws, size_t ws_size,
                              hipStream_t stream) {
    const float* x      = (const float*)d_in[0];
    const int*   target = (const int*)d_in[1];
    const float* W0     = (const float*)d_in[2];
    const float* b0     = (const float*)d_in[3];
    const float* Wh     = (const float*)d_in[4];
    const float* bh     = (const float*)d_in[5];
    const float* Wout   = (const float*)d_in[6];
    const float* bout   = (const float*)d_in[7];
    float* out = (float*)d_out;

    hipFuncSetAttribute((const void*)pcnet_kernel,
                        hipFuncAttributeMaxDynamicSharedMemorySize, LDS_BYTES);

    dim3 grid(65536/128);   // 512 blocks, 128 samples each
    dim3 block(BLOCK);      // 8 waves x 16 samples
    pcnet_kernel<<<grid, block, LDS_BYTES, stream>>>(x, target, W0, b0, Wh, bh, Wout, bout, out);
}

// Round 4
// 1592.875 us; speedup vs baseline: 62.4999x; 1.1298x over previous
//
#include <hip/hip_runtime.h>
#include <stdint.h>

typedef __attribute__((ext_vector_type(8))) _Float16 half8;
typedef __attribute__((ext_vector_type(4))) float f32x4;
typedef __attribute__((ext_vector_type(4))) uint32_t uint4v;

#define LR 0.1f
#define BLOCK 512
#define PERM __builtin_amdgcn_perm

// LDS byte offsets
// WFRAG: [9 layers][2 dir][3 tiles][2 ks][64 lanes][16B] = 110592
#define WOUTP_OFF  110592   // pred B-frags: [2 ks][64][16B] = 2048
#define WOUTT_OFF  112640   // td10 B-frags: [3 tiles][64][16B] = 3072
#define BH_OFF_B   115712   // bh f32: 9*48*4 = 1728
#define BOUT_OFF_B 117440   // bout f32: 64
#define VT_OFF_B   117504   // per-wave transpose tile: 864 u32 = 3456B * 8 waves
#define VT_STRIDE  3456
#define LDS_BYTES  (VT_OFF_B + 8*VT_STRIDE)   // 145152

extern __shared__ unsigned char smem[];

#define F16BITS(VAL) ((uint32_t)__builtin_bit_cast(unsigned short, (_Float16)(VAL)))

// pack f32 -> (f16 hi << 16) | f16 lo  (2-term split)
#define PACK_SPLIT(VAL, W) do { \
  float _v0 = (VAL); \
  _Float16 _hh = (_Float16)_v0; \
  float _hf = (float)_hh; \
  W = (F16BITS(_v0 - _hf)) | ((uint32_t)__builtin_bit_cast(unsigned short, _hh) << 16); \
} while(0)

// build hi-half / lo-half gathered words from 8 packed u32s (SSA only, no allocas)
#define GATHER_HI(WA, WB, HU) do { \
  HU[0] = PERM(WA[1], WA[0], 0x07060302u); \
  HU[1] = PERM(WA[3], WA[2], 0x07060302u); \
  HU[2] = PERM(WB[1], WB[0], 0x07060302u); \
  HU[3] = PERM(WB[3], WB[2], 0x07060302u); \
} while(0)
#define GATHER_LO(WA, WB, LU) do { \
  LU[0] = PERM(WA[1], WA[0], 0x05040100u); \
  LU[1] = PERM(WA[3], WA[2], 0x05040100u); \
  LU[2] = PERM(WB[1], WB[0], 0x05040100u); \
  LU[3] = PERM(WB[3], WB[2], 0x05040100u); \
} while(0)

// 48x48 matvec for 16 samples via MFMA. SRC/DST: float[12] in C-layout
// (idx = tile*4 + r ; value of sample 4*bq+r, comp n+16*tile).
// WFB: byte base of B-frag storage (3 tiles x 2 ks x 64 lanes x 16B).
// SPLIT: 1 = 2-term f16 split A (accurate), 0 = single f16 A (for LR-damped paths).
#define MV48(SRC, WFB, BIASOFF, HASBIAS, SPLIT, DST) do { \
  _Pragma("unroll") \
  for (int _t = 0; _t < 3; ++_t) { \
    _Pragma("unroll") \
    for (int _r = 0; _r < 4; ++_r) { \
      uint32_t _w; \
      if (SPLIT) { PACK_SPLIT(SRC[_t*4+_r], _w); } \
      else { _w = F16BITS(SRC[_t*4+_r]) << 16; } \
      vtu[(4*bq+_r)*52 + n + 16*_t] = _w; \
    } \
  } \
  __builtin_amdgcn_fence(__ATOMIC_ACQ_REL, "wavefront"); \
  half8 _Ah0, _Ah1, _Al0, _Al1; \
  { \
    const uint32_t* _vp = vtu + n*52 + bq*8; \
    uint4v _wa = *(const uint4v*)_vp; \
    uint4v _wb = *(const uint4v*)(_vp + 4); \
    uint4v _hu; GATHER_HI(_wa, _wb, _hu); _Ah0 = __builtin_bit_cast(half8, _hu); \
    if (SPLIT) { uint4v _lu; GATHER_LO(_wa, _wb, _lu); _Al0 = __builtin_bit_cast(half8, _lu); } \
    _vp = vtu + n*52 + 32 + bq*8; \
    _wa = *(const uint4v*)_vp; \
    _wb = *(const uint4v*)(_vp + 4); \
    uint4v _hu2; GATHER_HI(_wa, _wb, _hu2); _Ah1 = __builtin_bit_cast(half8, _hu2); \
    if (SPLIT) { uint4v _lu2; GATHER_LO(_wa, _wb, _lu2); _Al1 = __builtin_bit_cast(half8, _lu2); } \
  } \
  _Pragma("unroll") \
  for (int _t = 0; _t < 3; ++_t) { \
    float _bv = (HASBIAS) ? bhf[(BIASOFF) + n + 16*_t] : 0.f; \
    f32x4 _acc = { _bv, _bv, _bv, _bv }; \
    half8 _B0 = *(const half8*)(smem + (WFB) + (_t*2+0)*1024 + lane*16); \
    half8 _B1 = *(const half8*)(smem + (WFB) + (_t*2+1)*1024 + lane*16); \
    _acc = __builtin_amdgcn_mfma_f32_16x16x32_f16(_Ah0, _B0, _acc, 0, 0, 0); \
    if (SPLIT) _acc = __builtin_amdgcn_mfma_f32_16x16x32_f16(_Al0, _B0, _acc, 0, 0, 0); \
    _acc = __builtin_amdgcn_mfma_f32_16x16x32_f16(_Ah1, _B1, _acc, 0, 0, 0); \
    if (SPLIT) _acc = __builtin_amdgcn_mfma_f32_16x16x32_f16(_Al1, _B1, _acc, 0, 0, 0); \
    _Pragma("unroll") \
    for (int _r = 0; _r < 4; ++_r) DST[_t*4+_r] = _acc[_r]; \
  } \
} while(0)

#define LAYER_STEP(I) do { \
  float _pre[12], _err[12], _me[12], _td[12]; \
  MV48(v[(I)-1], ((I)-1)*12288, ((I)-1)*48, 1, 1, _pre); \
  _Pragma("unroll") \
  for (int _q = 0; _q < 12; ++_q) { \
    float _rl = fmaxf(_pre[_q], 0.f); \
    _err[_q] = v[I][_q] - _rl; \
    _me[_q] = (_pre[_q] > 0.f) ? _err[_q] : 0.f; \
  } \
  MV48(_me, ((I)-1)*12288 + 6144, 0, 0, 0, _td); \
  _Pragma("unroll") \
  for (int _q = 0; _q < 12; ++_q) { \
    float _nv = v[(I)-1][_q] - LR*(ep[_q] - _td[_q]); \
    v[(I)-1][_q] = fminf(fmaxf(_nv, -10.f), 10.f); \
    ep[_q] = _err[_q]; \
  } \
} while(0)

#define FWD(I) do { \
  float _pre[12]; \
  MV48(v[(I)-1], ((I)-1)*12288, ((I)-1)*48, 1, 1, _pre); \
  _Pragma("unroll") \
  for (int _q = 0; _q < 12; ++_q) v[I][_q] = fmaxf(_pre[_q], 0.f); \
} while(0)

__global__ __launch_bounds__(BLOCK, 2) __attribute__((amdgpu_waves_per_eu(2, 2)))
void pcnet_kernel(const float* __restrict__ x, const int* __restrict__ target,
                  const float* __restrict__ W0, const float* __restrict__ b0,
                  const float* __restrict__ Wh, const float* __restrict__ bh,
                  const float* __restrict__ Wout, const float* __restrict__ bout,
                  float* __restrict__ out)
{
    const int t = threadIdx.x;
    const int lane = t & 63;
    const int wv = t >> 6;
    float* ldsf = (float*)smem;
    const float* bhf = (const float*)(smem + BH_OFF_B);
    const float* boutf = (const float*)(smem + BOUT_OFF_B);

    const int bsamp0 = blockIdx.x*128 + wv*16;   // wave's first sample

    // ======== phase 0: a0 = relu(x@W0^T + b0), 4-lane-quarter mapping ========
    const int g = lane & 3, sloc = lane >> 2;
    const int bOld = bsamp0 + sloc;
    const int j0 = g*12;
    float acc0[12];
    #pragma unroll
    for (int jj = 0; jj < 12; jj++) acc0[jj] = b0[j0+jj];
    for (int ch = 0; ch < 7; ch++) {
        __syncthreads();
        for (int idx = t; idx < 112*48; idx += BLOCK) {
            int j = idx / 112, kl = idx - j*112;
            ldsf[kl*48 + j] = W0[j*784 + ch*112 + kl];
        }
        __syncthreads();
        const float* xb = x + (size_t)bOld*784 + ch*112;
        for (int k4 = 0; k4 < 112; k4 += 4) {
            float4 xv = *(const float4*)(xb + k4);
            float xs[4] = {xv.x, xv.y, xv.z, xv.w};
            #pragma unroll
            for (int f = 0; f < 4; f++) {
                const float* wr = &ldsf[(k4+f)*48 + j0];
                #pragma unroll
                for (int jj = 0; jj < 12; jj++) acc0[jj] = fmaf(wr[jj], xs[f], acc0[jj]);
            }
        }
    }

    // remap a0 -> C-layout via per-wave VT tile (f32 view)
    float* vtf = (float*)(smem + VT_OFF_B + wv*VT_STRIDE);
    uint32_t* vtu = (uint32_t*)(smem + VT_OFF_B + wv*VT_STRIDE);
    #pragma unroll
    for (int jj = 0; jj < 12; jj++) vtf[sloc*52 + j0 + jj] = fmaxf(acc0[jj], 0.f);
    __builtin_amdgcn_fence(__ATOMIC_ACQ_REL, "wavefront");

    const int bq = lane >> 4;    // 0..3: sample block in frag
    const int n  = lane & 15;    // col within tile
    float v[10][12], a0r[12];
    #pragma unroll
    for (int tt = 0; tt < 3; tt++)
        #pragma unroll
        for (int r = 0; r < 4; r++) {
            float val = vtf[(4*bq+r)*52 + n + 16*tt];
            a0r[tt*4+r] = val; v[0][tt*4+r] = val;
        }

    // zero VT pad columns 48..51 and tail pad (avoid NaN garbage in MFMA reads)
    vtu[(lane>>2)*52 + 48 + (lane&3)] = 0u;
    if (lane < 32) vtu[832 + lane] = 0u;

    __syncthreads();

    // ======== stage weight frags (f16, frag-order: conflict-free 16B/lane) ========
    for (int slot = t; slot < 6912; slot += BLOCK) {
        int L = slot / 768; int rem = slot % 768;
        int dir = rem / 384; rem %= 384;
        int tl = rem / 128; rem %= 128;
        int ks = rem / 64; int LB = rem % 64;
        int row = tl*16 + (LB & 15);
        int k0 = ks*32 + (LB >> 4)*8;
        half8 hv;
        #pragma unroll
        for (int j = 0; j < 8; j++) {
            int k = k0 + j;
            float w = 0.f;
            if (k < 48) w = (dir == 0) ? Wh[L*2304 + row*48 + k] : Wh[L*2304 + k*48 + row];
            hv[j] = (_Float16)w;
        }
        *(half8*)(smem + (L*2+dir)*6144 + (tl*2+ks)*1024 + LB*16) = hv;
    }
    for (int slot = t; slot < 5*64; slot += BLOCK) {
        int which = slot / 64; int LB = slot % 64;
        half8 hv;
        if (which < 2) {          // pred B: ks = which; rows = out class c
            int c = LB & 15; int k0 = which*32 + (LB>>4)*8;
            #pragma unroll
            for (int j = 0; j < 8; j++) { int k = k0+j; hv[j] = (_Float16)((c < 10 && k < 48) ? Wout[c*48+k] : 0.f); }
            *(half8*)(smem + WOUTP_OFF + which*1024 + LB*16) = hv;
        } else {                  // td10 B tiles: rows = hidden comp, K = class (pad 32)
            int tl = which - 2; int row = tl*16 + (LB & 15); int c0 = (LB>>4)*8;
            #pragma unroll
            for (int j = 0; j < 8; j++) { int c = c0+j; hv[j] = (_Float16)((c < 10) ? Wout[c*48+row] : 0.f); }
            *(half8*)(smem + WOUTT_OFF + tl*1024 + LB*16) = hv;
        }
    }
    for (int idx = t; idx < 432; idx += BLOCK) ((float*)(smem+BH_OFF_B))[idx] = bh[idx];
    if (t < 10) ((float*)(smem+BOUT_OFF_B))[t] = bout[t];
    __syncthreads();

    // targets for this lane's 4 samples
    int tg[4];
    #pragma unroll
    for (int r = 0; r < 4; r++) tg[r] = target[bsamp0 + 4*bq + r];

    // ======== forward init layers 1..9 ========
    FWD(1); FWD(2); FWD(3); FWD(4); FWD(5); FWD(6); FWD(7); FWD(8); FWD(9);

    // ======== settling ========
    #pragma unroll 1
    for (int s = 0; s < 20; ++s) {
        float ep[12];
        #pragma unroll
        for (int q = 0; q < 12; q++) ep[q] = v[0][q] - a0r[q];

        LAYER_STEP(1); LAYER_STEP(2); LAYER_STEP(3); LAYER_STEP(4); LAYER_STEP(5);
        LAYER_STEP(6); LAYER_STEP(7); LAYER_STEP(8); LAYER_STEP(9);

        // ---- output layer (all single-f16: LR-damped) ----
        {
            #pragma unroll
            for (int tt = 0; tt < 3; tt++)
                #pragma unroll
                for (int r = 0; r < 4; r++)
                    vtu[(4*bq+r)*52 + n + 16*tt] = F16BITS(v[9][tt*4+r]) << 16;
            __builtin_amdgcn_fence(__ATOMIC_ACQ_REL, "wavefront");
            half8 Ah0, Ah1;
            {
                const uint32_t* vp = vtu + n*52 + bq*8;
                uint4v wa = *(const uint4v*)vp;
                uint4v wb = *(const uint4v*)(vp + 4);
                uint4v hu; GATHER_HI(wa, wb, hu); Ah0 = __builtin_bit_cast(half8, hu);
                vp = vtu + n*52 + 32 + bq*8;
                wa = *(const uint4v*)vp;
                wb = *(const uint4v*)(vp + 4);
                uint4v hu2; GATHER_HI(wa, wb, hu2); Ah1 = __builtin_bit_cast(half8, hu2);
            }
            float bo = (n < 10) ? boutf[n] : 0.f;
            f32x4 acc = {bo, bo, bo, bo};
            {
                half8 B0 = *(const half8*)(smem + WOUTP_OFF + lane*16);
                half8 B1 = *(const half8*)(smem + WOUTP_OFF + 1024 + lane*16);
                acc = __builtin_amdgcn_mfma_f32_16x16x32_f16(Ah0, B0, acc, 0, 0, 0);
                acc = __builtin_amdgcn_mfma_f32_16x16x32_f16(Ah1, B1, acc, 0, 0, 0);
            }
            // e10 -> VT cols 0..15 (cols 16..31 stale but finite; B rows c>=10 are zero)
            #pragma unroll
            for (int r = 0; r < 4; r++) {
                float e = 0.f;
                if (n < 10) e = ((n == tg[r]) ? 1.f : 0.f) - acc[r];
                vtu[(4*bq+r)*52 + n] = F16BITS(e) << 16;
            }
            __builtin_amdgcn_fence(__ATOMIC_ACQ_REL, "wavefront");
            half8 eAh;
            {
                const uint32_t* vp = vtu + n*52 + bq*8;
                uint4v wa = *(const uint4v*)vp;
                uint4v wb = *(const uint4v*)(vp + 4);
                uint4v hu; GATHER_HI(wa, wb, hu); eAh = __builtin_bit_cast(half8, hu);
            }
            float td10[12];
            #pragma unroll
            for (int tt = 0; tt < 3; tt++) {
                f32x4 a2 = {0.f, 0.f, 0.f, 0.f};
                half8 B = *(const half8*)(smem + WOUTT_OFF + tt*1024 + lane*16);
                a2 = __builtin_amdgcn_mfma_f32_16x16x32_f16(eAh, B, a2, 0, 0, 0);
                #pragma unroll
                for (int r = 0; r < 4; r++) td10[tt*4+r] = a2[r];
            }
            #pragma unroll
            for (int q = 0; q < 12; q++) {
                float nv = v[9][q] - LR*(ep[q] - td10[q]);
                v[9][q] = fminf(fmaxf(nv, -10.f), 10.f);
            }
        }
    }

    // ======== write V ========
    #pragma unroll
    for (int L2 = 0; L2 < 10; L2++)
        #pragma unroll
        for (int tt = 0; tt < 3; tt++)
            #pragma unroll
            for (int r = 0; r < 4; r++)
                out[(size_t)L2*65536*48 + (size_t)(bsamp0 + 4*bq + r)*48 + n + 16*tt] = v[L2][tt*4+r];
}

extern "C" void kernel_launch(void* const* d_in, const int* in_sizes, int n_in,
                              void* d_out, int out_size, void* d_ws, size_t ws_size,
                              hipStream_t stream) {
    const float* x      = (const float*)d_in[0];
    const int*   target = (const int*)d_in[1];
    const float* W0     = (const float*)d_in[2];
    const float* b0     = (const float*)d_in[3];
    const float* Wh     = (const float*)d_in[4];
    const float* bh     = (const float*)d_in[5];
    const float* Wout   = (const float*)d_in[6];
    const float* bout   = (const float*)d_in[7];
    float* out = (float*)d_out;

    hipFuncSetAttribute((const void*)pcnet_kernel,
                        hipFuncAttributeMaxDynamicSharedMemorySize, LDS_BYTES);

    dim3 grid(65536/128);   // 512 blocks, 128 samples each
    dim3 block(BLOCK);      // 8 waves x 16 samples
    pcnet_kernel<<<grid, block, LDS_BYTES, stream>>>(x, target, W0, b0, Wh, bh, Wout, bout, out);
}

// Round 5
// 1048.254 us; speedup vs baseline: 94.9717x; 1.5196x over previous
//
#include <hip/hip_runtime.h>
#include <stdint.h>

typedef __attribute__((ext_vector_type(8))) _Float16 half8;
typedef __attribute__((ext_vector_type(4))) float f32x4;
typedef __attribute__((ext_vector_type(4))) uint32_t uint4v;

#define LR 0.1f
#define BLOCK 256
#define PERM __builtin_amdgcn_perm

// LDS byte offsets
// WFRAG: [9 layers][2 dir][3 tiles][2 ks][64 lanes][16B] = 110592
#define WOUTP_OFF  110592   // pred B-frags: [2 ks][64][16B] = 2048
#define WOUTT_OFF  112640   // td10 B-frags: [3 tiles][64][16B] = 3072
#define BH_OFF_B   115712   // bh f32: 9*48*4 = 1728
#define BOUT_OFF_B 117440   // bout f32: 64
#define VT_OFF_B   117504   // per-wave transpose tile: 864 u32 = 3456B * 4 waves
#define VT_STRIDE  3456
#define LDS_BYTES  (VT_OFF_B + 4*VT_STRIDE)   // 131328

extern __shared__ unsigned char smem[];

#define F16BITS(VAL) ((uint32_t)__builtin_bit_cast(unsigned short, (_Float16)(VAL)))

// pack f32 -> (f16 hi << 16) | f16 lo  (2-term split)
#define PACK_SPLIT(VAL, W) do { \
  float _v0 = (VAL); \
  _Float16 _hh = (_Float16)_v0; \
  float _hf = (float)_hh; \
  W = (F16BITS(_v0 - _hf)) | ((uint32_t)__builtin_bit_cast(unsigned short, _hh) << 16); \
} while(0)

// build hi-half / lo-half gathered words from 8 packed u32s (SSA only, no allocas)
#define GATHER_HI(WA, WB, HU) do { \
  HU[0] = PERM(WA[1], WA[0], 0x07060302u); \
  HU[1] = PERM(WA[3], WA[2], 0x07060302u); \
  HU[2] = PERM(WB[1], WB[0], 0x07060302u); \
  HU[3] = PERM(WB[3], WB[2], 0x07060302u); \
} while(0)
#define GATHER_LO(WA, WB, LU) do { \
  LU[0] = PERM(WA[1], WA[0], 0x05040100u); \
  LU[1] = PERM(WA[3], WA[2], 0x05040100u); \
  LU[2] = PERM(WB[1], WB[0], 0x05040100u); \
  LU[3] = PERM(WB[3], WB[2], 0x05040100u); \
} while(0)

// 48x48 matvec for 16 samples via MFMA. SRC/DST: float[12] in C-layout
// (idx = tile*4 + r ; value of sample 4*bq+r, comp n+16*tile).
// WFB: byte base of B-frag storage (3 tiles x 2 ks x 64 lanes x 16B).
// SPLIT: 1 = 2-term f16 split A (accurate), 0 = single f16 A (LR-damped paths).
#define MV48(SRC, WFB, BIASOFF, HASBIAS, SPLIT, DST) do { \
  _Pragma("unroll") \
  for (int _t = 0; _t < 3; ++_t) { \
    _Pragma("unroll") \
    for (int _r = 0; _r < 4; ++_r) { \
      uint32_t _w; \
      if (SPLIT) { PACK_SPLIT(SRC[_t*4+_r], _w); } \
      else { _w = F16BITS(SRC[_t*4+_r]) << 16; } \
      vtu[(4*bq+_r)*52 + n + 16*_t] = _w; \
    } \
  } \
  __builtin_amdgcn_fence(__ATOMIC_ACQ_REL, "wavefront"); \
  half8 _Ah0, _Ah1, _Al0, _Al1; \
  { \
    const uint32_t* _vp = vtu + n*52 + bq*8; \
    uint4v _wa = *(const uint4v*)_vp; \
    uint4v _wb = *(const uint4v*)(_vp + 4); \
    uint4v _hu; GATHER_HI(_wa, _wb, _hu); _Ah0 = __builtin_bit_cast(half8, _hu); \
    if (SPLIT) { uint4v _lu; GATHER_LO(_wa, _wb, _lu); _Al0 = __builtin_bit_cast(half8, _lu); } \
    _vp = vtu + n*52 + 32 + bq*8; \
    _wa = *(const uint4v*)_vp; \
    _wb = *(const uint4v*)(_vp + 4); \
    uint4v _hu2; GATHER_HI(_wa, _wb, _hu2); _Ah1 = __builtin_bit_cast(half8, _hu2); \
    if (SPLIT) { uint4v _lu2; GATHER_LO(_wa, _wb, _lu2); _Al1 = __builtin_bit_cast(half8, _lu2); } \
  } \
  _Pragma("unroll") \
  for (int _t = 0; _t < 3; ++_t) { \
    float _bv = (HASBIAS) ? bhf[(BIASOFF) + n + 16*_t] : 0.f; \
    f32x4 _acc = { _bv, _bv, _bv, _bv }; \
    half8 _B0 = *(const half8*)(smem + (WFB) + (_t*2+0)*1024 + lane*16); \
    half8 _B1 = *(const half8*)(smem + (WFB) + (_t*2+1)*1024 + lane*16); \
    _acc = __builtin_amdgcn_mfma_f32_16x16x32_f16(_Ah0, _B0, _acc, 0, 0, 0); \
    if (SPLIT) _acc = __builtin_amdgcn_mfma_f32_16x16x32_f16(_Al0, _B0, _acc, 0, 0, 0); \
    _acc = __builtin_amdgcn_mfma_f32_16x16x32_f16(_Ah1, _B1, _acc, 0, 0, 0); \
    if (SPLIT) _acc = __builtin_amdgcn_mfma_f32_16x16x32_f16(_Al1, _B1, _acc, 0, 0, 0); \
    _Pragma("unroll") \
    for (int _r = 0; _r < 4; ++_r) DST[_t*4+_r] = _acc[_r]; \
  } \
} while(0)

#define LAYER_STEP(I) do { \
  float _pre[12], _err[12], _me[12], _td[12]; \
  MV48(v[(I)-1], ((I)-1)*12288, ((I)-1)*48, 1, 1, _pre); \
  _Pragma("unroll") \
  for (int _q = 0; _q < 12; ++_q) { \
    float _rl = fmaxf(_pre[_q], 0.f); \
    _err[_q] = v[I][_q] - _rl; \
    _me[_q] = (_pre[_q] > 0.f) ? _err[_q] : 0.f; \
  } \
  MV48(_me, ((I)-1)*12288 + 6144, 0, 0, 0, _td); \
  _Pragma("unroll") \
  for (int _q = 0; _q < 12; ++_q) { \
    float _nv = v[(I)-1][_q] - LR*(ep[_q] - _td[_q]); \
    v[(I)-1][_q] = fminf(fmaxf(_nv, -10.f), 10.f); \
    ep[_q] = _err[_q]; \
  } \
} while(0)

#define FWD(I) do { \
  float _pre[12]; \
  MV48(v[(I)-1], ((I)-1)*12288, ((I)-1)*48, 1, 1, _pre); \
  _Pragma("unroll") \
  for (int _q = 0; _q < 12; ++_q) v[I][_q] = fmaxf(_pre[_q], 0.f); \
} while(0)

__global__ __launch_bounds__(BLOCK) __attribute__((amdgpu_waves_per_eu(1, 1)))
void pcnet_kernel(const float* __restrict__ x, const int* __restrict__ target,
                  const float* __restrict__ W0, const float* __restrict__ b0,
                  const float* __restrict__ Wh, const float* __restrict__ bh,
                  const float* __restrict__ Wout, const float* __restrict__ bout,
                  float* __restrict__ out)
{
    const int t = threadIdx.x;
    const int lane = t & 63;
    const int wv = t >> 6;
    float* ldsf = (float*)smem;
    const float* bhf = (const float*)(smem + BH_OFF_B);
    const float* boutf = (const float*)(smem + BOUT_OFF_B);

    const int bsamp0 = blockIdx.x*64 + wv*16;   // wave's first sample

    // ======== phase 0: a0 = relu(x@W0^T + b0), 4-lane-quarter mapping ========
    const int g = lane & 3, sloc = lane >> 2;
    const int bOld = bsamp0 + sloc;
    const int j0 = g*12;
    float acc0[12];
    #pragma unroll
    for (int jj = 0; jj < 12; jj++) acc0[jj] = b0[j0+jj];
    for (int ch = 0; ch < 7; ch++) {
        __syncthreads();
        for (int idx = t; idx < 112*48; idx += BLOCK) {
            int j = idx / 112, kl = idx - j*112;
            ldsf[kl*48 + j] = W0[j*784 + ch*112 + kl];
        }
        __syncthreads();
        const float* xb = x + (size_t)bOld*784 + ch*112;
        for (int k4 = 0; k4 < 112; k4 += 4) {
            float4 xv = *(const float4*)(xb + k4);
            float xs[4] = {xv.x, xv.y, xv.z, xv.w};
            #pragma unroll
            for (int f = 0; f < 4; f++) {
                const float* wr = &ldsf[(k4+f)*48 + j0];
                #pragma unroll
                for (int jj = 0; jj < 12; jj++) acc0[jj] = fmaf(wr[jj], xs[f], acc0[jj]);
            }
        }
    }

    // remap a0 -> C-layout via per-wave VT tile (f32 view)
    float* vtf = (float*)(smem + VT_OFF_B + wv*VT_STRIDE);
    uint32_t* vtu = (uint32_t*)(smem + VT_OFF_B + wv*VT_STRIDE);
    #pragma unroll
    for (int jj = 0; jj < 12; jj++) vtf[sloc*52 + j0 + jj] = fmaxf(acc0[jj], 0.f);
    __builtin_amdgcn_fence(__ATOMIC_ACQ_REL, "wavefront");

    const int bq = lane >> 4;    // 0..3: sample block in frag
    const int n  = lane & 15;    // col within tile
    float v[10][12], a0r[12];
    #pragma unroll
    for (int tt = 0; tt < 3; tt++)
        #pragma unroll
        for (int r = 0; r < 4; r++) {
            float val = vtf[(4*bq+r)*52 + n + 16*tt];
            a0r[tt*4+r] = val; v[0][tt*4+r] = val;
        }

    // zero VT pad columns 48..51 and tail pad (avoid NaN garbage in MFMA reads)
    vtu[(lane>>2)*52 + 48 + (lane&3)] = 0u;
    if (lane < 32) vtu[832 + lane] = 0u;

    __syncthreads();

    // ======== stage weight frags (f16, frag-order: conflict-free 16B/lane) ========
    for (int slot = t; slot < 6912; slot += BLOCK) {
        int L = slot / 768; int rem = slot % 768;
        int dir = rem / 384; rem %= 384;
        int tl = rem / 128; rem %= 128;
        int ks = rem / 64; int LB = rem % 64;
        int row = tl*16 + (LB & 15);
        int k0 = ks*32 + (LB >> 4)*8;
        half8 hv;
        #pragma unroll
        for (int j = 0; j < 8; j++) {
            int k = k0 + j;
            float w = 0.f;
            if (k < 48) w = (dir == 0) ? Wh[L*2304 + row*48 + k] : Wh[L*2304 + k*48 + row];
            hv[j] = (_Float16)w;
        }
        *(half8*)(smem + (L*2+dir)*6144 + (tl*2+ks)*1024 + LB*16) = hv;
    }
    for (int slot = t; slot < 5*64; slot += BLOCK) {
        int which = slot / 64; int LB = slot % 64;
        half8 hv;
        if (which < 2) {          // pred B: ks = which; rows = out class c
            int c = LB & 15; int k0 = which*32 + (LB>>4)*8;
            #pragma unroll
            for (int j = 0; j < 8; j++) { int k = k0+j; hv[j] = (_Float16)((c < 10 && k < 48) ? Wout[c*48+k] : 0.f); }
            *(half8*)(smem + WOUTP_OFF + which*1024 + LB*16) = hv;
        } else {                  // td10 B tiles: rows = hidden comp, K = class (pad 32)
            int tl = which - 2; int row = tl*16 + (LB & 15); int c0 = (LB>>4)*8;
            #pragma unroll
            for (int j = 0; j < 8; j++) { int c = c0+j; hv[j] = (_Float16)((c < 10) ? Wout[c*48+row] : 0.f); }
            *(half8*)(smem + WOUTT_OFF + tl*1024 + LB*16) = hv;
        }
    }
    for (int idx = t; idx < 432; idx += BLOCK) ((float*)(smem+BH_OFF_B))[idx] = bh[idx];
    if (t < 10) ((float*)(smem+BOUT_OFF_B))[t] = bout[t];
    __syncthreads();

    // targets for this lane's 4 samples
    int tg[4];
    #pragma unroll
    for (int r = 0; r < 4; r++) tg[r] = target[bsamp0 + 4*bq + r];

    // ======== forward init layers 1..9 ========
    FWD(1); FWD(2); FWD(3); FWD(4); FWD(5); FWD(6); FWD(7); FWD(8); FWD(9);

    // ======== settling ========
    #pragma unroll 1
    for (int s = 0; s < 20; ++s) {
        float ep[12];
        #pragma unroll
        for (int q = 0; q < 12; q++) ep[q] = v[0][q] - a0r[q];

        LAYER_STEP(1); LAYER_STEP(2); LAYER_STEP(3); LAYER_STEP(4); LAYER_STEP(5);
        LAYER_STEP(6); LAYER_STEP(7); LAYER_STEP(8); LAYER_STEP(9);

        // ---- output layer (all single-f16: LR-damped) ----
        {
            #pragma unroll
            for (int tt = 0; tt < 3; tt++)
                #pragma unroll
                for (int r = 0; r < 4; r++)
                    vtu[(4*bq+r)*52 + n + 16*tt] = F16BITS(v[9][tt*4+r]) << 16;
            __builtin_amdgcn_fence(__ATOMIC_ACQ_REL, "wavefront");
            half8 Ah0, Ah1;
            {
                const uint32_t* vp = vtu + n*52 + bq*8;
                uint4v wa = *(const uint4v*)vp;
                uint4v wb = *(const uint4v*)(vp + 4);
                uint4v hu; GATHER_HI(wa, wb, hu); Ah0 = __builtin_bit_cast(half8, hu);
                vp = vtu + n*52 + 32 + bq*8;
                wa = *(const uint4v*)vp;
                wb = *(const uint4v*)(vp + 4);
                uint4v hu2; GATHER_HI(wa, wb, hu2); Ah1 = __builtin_bit_cast(half8, hu2);
            }
            float bo = (n < 10) ? boutf[n] : 0.f;
            f32x4 acc = {bo, bo, bo, bo};
            {
                half8 B0 = *(const half8*)(smem + WOUTP_OFF + lane*16);
                half8 B1 = *(const half8*)(smem + WOUTP_OFF + 1024 + lane*16);
                acc = __builtin_amdgcn_mfma_f32_16x16x32_f16(Ah0, B0, acc, 0, 0, 0);
                acc = __builtin_amdgcn_mfma_f32_16x16x32_f16(Ah1, B1, acc, 0, 0, 0);
            }
            // e10 -> VT cols 0..15 (cols 16..31 stale but finite; B rows c>=10 are zero)
            #pragma unroll
            for (int r = 0; r < 4; r++) {
                float e = 0.f;
                if (n < 10) e = ((n == tg[r]) ? 1.f : 0.f) - acc[r];
                vtu[(4*bq+r)*52 + n] = F16BITS(e) << 16;
            }
            __builtin_amdgcn_fence(__ATOMIC_ACQ_REL, "wavefront");
            half8 eAh;
            {
                const uint32_t* vp = vtu + n*52 + bq*8;
                uint4v wa = *(const uint4v*)vp;
                uint4v wb = *(const uint4v*)(vp + 4);
                uint4v hu; GATHER_HI(wa, wb, hu); eAh = __builtin_bit_cast(half8, hu);
            }
            float td10[12];
            #pragma unroll
            for (int tt = 0; tt < 3; tt++) {
                f32x4 a2 = {0.f, 0.f, 0.f, 0.f};
                half8 B = *(const half8*)(smem + WOUTT_OFF + tt*1024 + lane*16);
                a2 = __builtin_amdgcn_mfma_f32_16x16x32_f16(eAh, B, a2, 0, 0, 0);
                #pragma unroll
                for (int r = 0; r < 4; r++) td10[tt*4+r] = a2[r];
            }
            #pragma unroll
            for (int q = 0; q < 12; q++) {
                float nv = v[9][q] - LR*(ep[q] - td10[q]);
                v[9][q] = fminf(fmaxf(nv, -10.f), 10.f);
            }
        }
    }

    // ======== write V ========
    #pragma unroll
    for (int L2 = 0; L2 < 10; L2++)
        #pragma unroll
        for (int tt = 0; tt < 3; tt++)
            #pragma unroll
            for (int r = 0; r < 4; r++)
                out[(size_t)L2*65536*48 + (size_t)(bsamp0 + 4*bq + r)*48 + n + 16*tt] = v[L2][tt*4+r];
}

extern "C" void kernel_launch(void* const* d_in, const int* in_sizes, int n_in,
                              void* d_out, int out_size, void* d_ws, size_t ws_size,
                              hipStream_t stream) {
    const float* x      = (const float*)d_in[0];
    const int*   target = (const int*)d_in[1];
    const float* W0     = (const float*)d_in[2];
    const float* b0     = (const float*)d_in[3];
    const float* Wh     = (const float*)d_in[4];
    const float* bh     = (const float*)d_in[5];
    const float* Wout   = (const float*)d_in[6];
    const float* bout   = (const float*)d_in[7];
    float* out = (float*)d_out;

    hipFuncSetAttribute((const void*)pcnet_kernel,
                        hipFuncAttributeMaxDynamicSharedMemorySize, LDS_BYTES);

    dim3 grid(65536/64);    // 1024 blocks, 64 samples each
    dim3 block(BLOCK);      // 4 waves x 16 samples
    pcnet_kernel<<<grid, block, LDS_BYTES, stream>>>(x, target, W0, b0, Wh, bh, Wout, bout, out);
}